// Round 1
// baseline (1665.661 us; speedup 1.0000x reference)
//
#include <hip/hip_runtime.h>
#include <hip/hip_bf16.h>

// Problem constants
#define BB 2
#define SS 2048
#define DM 1024
#define KVD 512
#define NH 8
#define NQ 2
#define QH 16
#define DH 64
#define MROWS 4096   // B*S

__device__ __forceinline__ float elu_f(float x) {
    return x > 0.0f ? x : (__expf(x) - 1.0f);
}

// ---------------------------------------------------------------------------
// Kernel 1: fused QKV projection.  C[M=4096][N=2048] = x @ [Wq | Wk | Wv]
// 64x64 tile, BK=16, 256 threads, 4x4 per thread.
// ---------------------------------------------------------------------------
__global__ __launch_bounds__(256) void gemm_qkv(
        const float* __restrict__ x, const float* __restrict__ Wq,
        const float* __restrict__ Wk, const float* __restrict__ Wv,
        float* __restrict__ q, float* __restrict__ k, float* __restrict__ v) {
    __shared__ float As[16][65];
    __shared__ float Bs[16][65];
    const int n0 = blockIdx.x * 64;
    const int m0 = blockIdx.y * 64;

    const float* W; int ldb, c0; float* out; int ldo, oc0;
    if (n0 < 1024)      { W = Wq; ldb = 1024; c0 = n0;        out = q; ldo = 1024; oc0 = n0; }
    else if (n0 < 1536) { W = Wk; ldb = 512;  c0 = n0 - 1024; out = k; ldo = 512;  oc0 = n0 - 1024; }
    else                { W = Wv; ldb = 512;  c0 = n0 - 1536; out = v; ldo = 512;  oc0 = n0 - 1536; }

    const int tid = threadIdx.x;
    const int tx = tid & 15, ty = tid >> 4;
    float acc[4][4] = {};

    for (int k0 = 0; k0 < DM; k0 += 16) {
        #pragma unroll
        for (int i = 0; i < 4; i++) {
            int e = tid + 256 * i;            // A tile: 64 rows x 16 k
            int mm = e >> 4, kk = e & 15;
            As[kk][mm] = x[(size_t)(m0 + mm) * DM + k0 + kk];
        }
        #pragma unroll
        for (int i = 0; i < 4; i++) {
            int e = tid + 256 * i;            // B tile: 16 k x 64 n
            int kk = e >> 6, nn = e & 63;
            Bs[kk][nn] = W[(size_t)(k0 + kk) * ldb + c0 + nn];
        }
        __syncthreads();
        #pragma unroll
        for (int kk = 0; kk < 16; kk++) {
            float a[4], b[4];
            #pragma unroll
            for (int i = 0; i < 4; i++) a[i] = As[kk][ty * 4 + i];
            #pragma unroll
            for (int j = 0; j < 4; j++) b[j] = Bs[kk][tx * 4 + j];
            #pragma unroll
            for (int i = 0; i < 4; i++)
                #pragma unroll
                for (int j = 0; j < 4; j++)
                    acc[i][j] += a[i] * b[j];
        }
        __syncthreads();
    }
    #pragma unroll
    for (int i = 0; i < 4; i++)
        #pragma unroll
        for (int j = 0; j < 4; j++)
            out[(size_t)(m0 + ty * 4 + i) * ldo + oc0 + tx * 4 + j] = acc[i][j];
}

// ---------------------------------------------------------------------------
// Kernel 2: flash attention (non-causal), fp32.
// grid.x = S/64 query blocks, grid.y = B*QH. 256 threads, 4x4 per thread.
// Writes a_dot with layout (b, s, qh*64+d) == out layout.
// ---------------------------------------------------------------------------
__global__ __launch_bounds__(256) void flash_attn(
        const float* __restrict__ q, const float* __restrict__ kbuf,
        const float* __restrict__ vbuf, float* __restrict__ a_dot) {
    __shared__ float Qs[64][65];  // [kk][r], pre-scaled
    __shared__ float Ks[64][65];  // [kk][t]
    __shared__ float Vs[64][65];  // [t][d]
    __shared__ float Ps[64][65];  // [t][r]

    const int r0 = blockIdx.x * 64;
    const int bh = blockIdx.y;
    const int b = bh >> 4, qh = bh & 15;
    const int kvh = qh >> 1;
    const int tid = threadIdx.x;
    const int tx = tid & 15, ty = tid >> 4;
    const float scale = 0.125f;  // 1/sqrt(64)

    // load Q block (transposed, scaled)
    #pragma unroll
    for (int i = 0; i < 16; i++) {
        int e = tid + 256 * i;
        int r = e >> 6, kk = e & 63;
        Qs[kk][r] = q[(size_t)(b * SS + r0 + r) * DM + qh * DH + kk] * scale;
    }

    float m_i[4], l_i[4], acc[4][4] = {};
    #pragma unroll
    for (int i = 0; i < 4; i++) { m_i[i] = -1e30f; l_i[i] = 0.0f; }

    for (int t0 = 0; t0 < SS; t0 += 64) {
        __syncthreads();
        #pragma unroll
        for (int i = 0; i < 16; i++) {
            int e = tid + 256 * i;
            int t = e >> 6, kk = e & 63;
            Ks[kk][t] = kbuf[(size_t)(b * SS + t0 + t) * KVD + kvh * DH + kk];
            Vs[t][kk] = vbuf[(size_t)(b * SS + t0 + t) * KVD + kvh * DH + kk];
        }
        __syncthreads();

        // S_tile = Q @ K^T
        float s[4][4] = {};
        #pragma unroll
        for (int kk = 0; kk < 64; kk++) {
            float a[4], bb[4];
            #pragma unroll
            for (int i = 0; i < 4; i++) a[i] = Qs[kk][ty * 4 + i];
            #pragma unroll
            for (int j = 0; j < 4; j++) bb[j] = Ks[kk][tx * 4 + j];
            #pragma unroll
            for (int i = 0; i < 4; i++)
                #pragma unroll
                for (int j = 0; j < 4; j++)
                    s[i][j] += a[i] * bb[j];
        }

        // online softmax per row (16 tx-threads own a row; contiguous 16 lanes)
        #pragma unroll
        for (int i = 0; i < 4; i++) {
            float rmax = fmaxf(fmaxf(s[i][0], s[i][1]), fmaxf(s[i][2], s[i][3]));
            #pragma unroll
            for (int off = 8; off >= 1; off >>= 1)
                rmax = fmaxf(rmax, __shfl_xor(rmax, off));
            float m_new = fmaxf(m_i[i], rmax);
            float p[4], rsum = 0.0f;
            #pragma unroll
            for (int j = 0; j < 4; j++) { p[j] = __expf(s[i][j] - m_new); rsum += p[j]; }
            #pragma unroll
            for (int off = 8; off >= 1; off >>= 1)
                rsum += __shfl_xor(rsum, off);
            float resc = __expf(m_i[i] - m_new);
            l_i[i] = l_i[i] * resc + rsum;
            #pragma unroll
            for (int j = 0; j < 4; j++) acc[i][j] *= resc;
            m_i[i] = m_new;
            // store P transposed: Ps[t][r]
            #pragma unroll
            for (int j = 0; j < 4; j++) Ps[tx * 4 + j][ty * 4 + i] = p[j];
        }
        __syncthreads();

        // acc += P @ V
        #pragma unroll
        for (int t = 0; t < 64; t++) {
            float pr[4], vv[4];
            #pragma unroll
            for (int i = 0; i < 4; i++) pr[i] = Ps[t][ty * 4 + i];
            #pragma unroll
            for (int j = 0; j < 4; j++) vv[j] = Vs[t][tx * 4 + j];
            #pragma unroll
            for (int i = 0; i < 4; i++)
                #pragma unroll
                for (int j = 0; j < 4; j++)
                    acc[i][j] += pr[i] * vv[j];
        }
    }

    #pragma unroll
    for (int i = 0; i < 4; i++) {
        float inv = 1.0f / l_i[i];
        #pragma unroll
        for (int j = 0; j < 4; j++)
            a_dot[(size_t)(b * SS + r0 + ty * 4 + i) * DM + qh * DH + tx * 4 + j] =
                acc[i][j] * inv;
    }
}

// ---------------------------------------------------------------------------
// Kernel 3: per-row dot of elu(src_row) with norm vector. One wave per row.
// Rows are 512 wide. den[row] = sum_c elu(src[row*512+c]) * norm[c]
// ---------------------------------------------------------------------------
__global__ __launch_bounds__(256) void row_dot(
        const float* __restrict__ src, const float* __restrict__ norm,
        float* __restrict__ den, int nrows) {
    const int wave = threadIdx.x >> 6, lane = threadIdx.x & 63;
    const int row = blockIdx.x * 4 + wave;
    if (row >= nrows) return;
    const float* p = src + (size_t)row * KVD;
    float s = 0.0f;
    #pragma unroll
    for (int j = 0; j < 8; j++) {
        int c = lane + 64 * j;
        s += elu_f(p[c]) * norm[c];
    }
    #pragma unroll
    for (int off = 32; off >= 1; off >>= 1) s += __shfl_xor(s, off);
    if (lane == 0) den[row] = s;
}

// ---------------------------------------------------------------------------
// Kernel 4: a_mem GEMM + gated fusion epilogue (writes final `out`).
// A = elu(q) viewed as 8192x512, B = memory 512x512.
// out_flat[m*512+n] = a_dot*(1-w) + (acc/den_q[m])*w
// ---------------------------------------------------------------------------
__global__ __launch_bounds__(256) void gemm_amem(
        const float* __restrict__ q, const float* __restrict__ memory,
        const float* __restrict__ a_dot, const float* __restrict__ den_q,
        const float* __restrict__ mw, float* __restrict__ out) {
    __shared__ float As[16][65];
    __shared__ float Bs[16][65];
    const int n0 = blockIdx.x * 64;
    const int m0 = blockIdx.y * 64;
    const int tid = threadIdx.x;
    const int tx = tid & 15, ty = tid >> 4;
    const float w = 1.0f / (1.0f + __expf(-mw[0]));
    float acc[4][4] = {};

    for (int k0 = 0; k0 < KVD; k0 += 16) {
        #pragma unroll
        for (int i = 0; i < 4; i++) {
            int e = tid + 256 * i;
            int mm = e >> 4, kk = e & 15;
            As[kk][mm] = elu_f(q[(size_t)(m0 + mm) * KVD + k0 + kk]);
        }
        #pragma unroll
        for (int i = 0; i < 4; i++) {
            int e = tid + 256 * i;
            int kk = e >> 6, nn = e & 63;
            Bs[kk][nn] = memory[(size_t)(k0 + kk) * KVD + n0 + nn];
        }
        __syncthreads();
        #pragma unroll
        for (int kk = 0; kk < 16; kk++) {
            float a[4], b[4];
            #pragma unroll
            for (int i = 0; i < 4; i++) a[i] = As[kk][ty * 4 + i];
            #pragma unroll
            for (int j = 0; j < 4; j++) b[j] = Bs[kk][tx * 4 + j];
            #pragma unroll
            for (int i = 0; i < 4; i++)
                #pragma unroll
                for (int j = 0; j < 4; j++)
                    acc[i][j] += a[i] * b[j];
        }
        __syncthreads();
    }
    #pragma unroll
    for (int i = 0; i < 4; i++) {
        int m = m0 + ty * 4 + i;
        float invden = 1.0f / den_q[m];
        #pragma unroll
        for (int j = 0; j < 4; j++) {
            size_t fo = (size_t)m * KVD + n0 + tx * 4 + j;
            out[fo] = a_dot[fo] * (1.0f - w) + acc[i][j] * invden * w;
        }
    }
}

// ---------------------------------------------------------------------------
// Kernel 5: u = v - (elu(k) @ memory) / den_k.  A = elu(k) 4096x512.
// ---------------------------------------------------------------------------
__global__ __launch_bounds__(256) void gemm_u(
        const float* __restrict__ kbuf, const float* __restrict__ memory,
        const float* __restrict__ vbuf, const float* __restrict__ den_k,
        float* __restrict__ u) {
    __shared__ float As[16][65];
    __shared__ float Bs[16][65];
    const int n0 = blockIdx.x * 64;
    const int m0 = blockIdx.y * 64;
    const int tid = threadIdx.x;
    const int tx = tid & 15, ty = tid >> 4;
    float acc[4][4] = {};

    for (int k0 = 0; k0 < KVD; k0 += 16) {
        #pragma unroll
        for (int i = 0; i < 4; i++) {
            int e = tid + 256 * i;
            int mm = e >> 4, kk = e & 15;
            As[kk][mm] = elu_f(kbuf[(size_t)(m0 + mm) * KVD + k0 + kk]);
        }
        #pragma unroll
        for (int i = 0; i < 4; i++) {
            int e = tid + 256 * i;
            int kk = e >> 6, nn = e & 63;
            Bs[kk][nn] = memory[(size_t)(k0 + kk) * KVD + n0 + nn];
        }
        __syncthreads();
        #pragma unroll
        for (int kk = 0; kk < 16; kk++) {
            float a[4], b[4];
            #pragma unroll
            for (int i = 0; i < 4; i++) a[i] = As[kk][ty * 4 + i];
            #pragma unroll
            for (int j = 0; j < 4; j++) b[j] = Bs[kk][tx * 4 + j];
            #pragma unroll
            for (int i = 0; i < 4; i++)
                #pragma unroll
                for (int j = 0; j < 4; j++)
                    acc[i][j] += a[i] * b[j];
        }
        __syncthreads();
    }
    #pragma unroll
    for (int i = 0; i < 4; i++) {
        int m = m0 + ty * 4 + i;
        float invden = 1.0f / den_k[m];
        #pragma unroll
        for (int j = 0; j < 4; j++) {
            size_t fo = (size_t)m * KVD + n0 + tx * 4 + j;
            u[fo] = vbuf[fo] - acc[i][j] * invden;
        }
    }
}

// ---------------------------------------------------------------------------
// Kernel 6/7: column sums of elu(k) -> new_memory_norm (two-stage, no atomics)
// ---------------------------------------------------------------------------
__global__ __launch_bounds__(256) void colsum_part(
        const float* __restrict__ kbuf, float* __restrict__ part) {
    const int blk = blockIdx.x;      // 32 blocks x 128 rows
    const int tid = threadIdx.x;
    float a0 = 0.0f, a1 = 0.0f;
    for (int r = 0; r < 128; r++) {
        size_t row = (size_t)(blk * 128 + r) * KVD;
        a0 += elu_f(kbuf[row + tid]);
        a1 += elu_f(kbuf[row + tid + 256]);
    }
    part[blk * KVD + tid] = a0;
    part[blk * KVD + tid + 256] = a1;
}

__global__ __launch_bounds__(256) void colsum_final(
        const float* __restrict__ part, const float* __restrict__ mnorm,
        float* __restrict__ out_norm) {
    const int c = blockIdx.x * 256 + threadIdx.x;
    float s = mnorm[c];
    for (int b = 0; b < 32; b++) s += part[b * KVD + c];
    out_norm[c] = s;
}

// ---------------------------------------------------------------------------
// Kernel 8: split-K delta GEMM: part[kc][i][j] = sum_{s in chunk} elu(k[s][i])*u[s][j]
// grid (8 n-tiles, 8 m-tiles, 8 k-chunks)
// ---------------------------------------------------------------------------
__global__ __launch_bounds__(256) void gemm_delta(
        const float* __restrict__ kbuf, const float* __restrict__ u,
        float* __restrict__ part) {
    __shared__ float As[16][65];  // [ss][i]
    __shared__ float Bs[16][65];  // [ss][j]
    const int j0 = blockIdx.x * 64;
    const int i0 = blockIdx.y * 64;
    const int kc = blockIdx.z;
    const int tid = threadIdx.x;
    const int tx = tid & 15, ty = tid >> 4;
    float acc[4][4] = {};

    for (int s0 = kc * 512; s0 < kc * 512 + 512; s0 += 16) {
        #pragma unroll
        for (int i = 0; i < 4; i++) {
            int e = tid + 256 * i;
            int ss = e >> 6, ii = e & 63;
            As[ss][ii] = elu_f(kbuf[(size_t)(s0 + ss) * KVD + i0 + ii]);
        }
        #pragma unroll
        for (int i = 0; i < 4; i++) {
            int e = tid + 256 * i;
            int ss = e >> 6, jj = e & 63;
            Bs[ss][jj] = u[(size_t)(s0 + ss) * KVD + j0 + jj];
        }
        __syncthreads();
        #pragma unroll
        for (int ss = 0; ss < 16; ss++) {
            float a[4], b[4];
            #pragma unroll
            for (int i = 0; i < 4; i++) a[i] = As[ss][ty * 4 + i];
            #pragma unroll
            for (int j = 0; j < 4; j++) b[j] = Bs[ss][tx * 4 + j];
            #pragma unroll
            for (int i = 0; i < 4; i++)
                #pragma unroll
                for (int j = 0; j < 4; j++)
                    acc[i][j] += a[i] * b[j];
        }
        __syncthreads();
    }
    #pragma unroll
    for (int i = 0; i < 4; i++)
        #pragma unroll
        for (int j = 0; j < 4; j++)
            part[(size_t)kc * (KVD * KVD) + (size_t)(i0 + ty * 4 + i) * KVD + j0 + tx * 4 + j]
                = acc[i][j];
}

__global__ __launch_bounds__(256) void delta_final(
        const float* __restrict__ part, const float* __restrict__ memory,
        float* __restrict__ out_mem) {
    const int idx = blockIdx.x * 256 + threadIdx.x;   // 262144 elements
    float s = memory[idx];
    #pragma unroll
    for (int kc = 0; kc < 8; kc++) s += part[(size_t)kc * (KVD * KVD) + idx];
    out_mem[idx] = s;
}

// ---------------------------------------------------------------------------
extern "C" void kernel_launch(void* const* d_in, const int* in_sizes, int n_in,
                              void* d_out, int out_size, void* d_ws, size_t ws_size,
                              hipStream_t stream) {
    const float* x      = (const float*)d_in[0];
    const float* Wq     = (const float*)d_in[1];
    const float* Wk     = (const float*)d_in[2];
    const float* Wv     = (const float*)d_in[3];
    const float* memory = (const float*)d_in[4];
    const float* mnorm  = (const float*)d_in[5];
    const float* mw     = (const float*)d_in[6];

    float* out_f   = (float*)d_out;                     // 4096x1024
    float* out_mem = out_f + (size_t)MROWS * DM;        // 512x512
    float* out_nrm = out_mem + (size_t)KVD * KVD;       // 512

    float* ws = (float*)d_ws;
    float* q      = ws;                                   // 4,194,304
    float* kbuf   = q + (size_t)MROWS * DM;               // 2,097,152
    float* vbuf   = kbuf + (size_t)MROWS * KVD;           // 2,097,152
    float* a_dot  = vbuf + (size_t)MROWS * KVD;           // 4,194,304
    float* u      = a_dot + (size_t)MROWS * DM;           // 2,097,152
    float* den_q  = u + (size_t)MROWS * KVD;              // 8192
    float* den_k  = den_q + 8192;                         // 4096
    float* cspart = den_k + 4096;                         // 32*512
    float* dpart  = q;  // q is dead after gemm_amem; reuse for 8*512*512 partials

    // 1. QKV projection
    gemm_qkv<<<dim3(32, 64), 256, 0, stream>>>(x, Wq, Wk, Wv, q, kbuf, vbuf);
    // 2. flash attention
    flash_attn<<<dim3(32, 32), 256, 0, stream>>>(q, kbuf, vbuf, a_dot);
    // 3. denominators
    row_dot<<<2048, 256, 0, stream>>>(q, mnorm, den_q, 8192);
    row_dot<<<1024, 256, 0, stream>>>(kbuf, mnorm, den_k, 4096);
    // 4. a_mem + fusion -> out  (last reader of q)
    gemm_amem<<<dim3(8, 128), 256, 0, stream>>>(q, memory, a_dot, den_q, mw, out_f);
    // 5. column sums -> new_memory_norm
    colsum_part<<<32, 256, 0, stream>>>(kbuf, cspart);
    colsum_final<<<2, 256, 0, stream>>>(cspart, mnorm, out_nrm);
    // 6. u = v - retrieved
    gemm_u<<<dim3(8, 64), 256, 0, stream>>>(kbuf, memory, vbuf, den_k, u);
    // 7. delta GEMM (split-K) + finalize -> new_memory
    gemm_delta<<<dim3(8, 8, 8), 256, 0, stream>>>(kbuf, u, dpart);
    delta_final<<<1024, 256, 0, stream>>>(dpart, memory, out_mem);
}

// Round 2
// 729.476 us; speedup vs baseline: 2.2834x; 2.2834x over previous
//
#include <hip/hip_runtime.h>
#include <hip/hip_bf16.h>

// Problem constants
#define BB 2
#define SS 2048
#define DM 1024
#define KVD 512
#define NH 8
#define NQ 2
#define QH 16
#define DH 64
#define MROWS 4096   // B*S

typedef float f32x4 __attribute__((ext_vector_type(4)));
typedef short short8 __attribute__((ext_vector_type(8)));

__device__ __forceinline__ float elu_f(float x) {
    return x > 0.0f ? x : (__expf(x) - 1.0f);
}

// float -> bf16 (round to nearest even), as raw short
__device__ __forceinline__ short f2bf(float f) {
    union { float f; unsigned u; } v; v.f = f;
    unsigned r = v.u + 0x7FFFu + ((v.u >> 16) & 1u);
    return (short)(r >> 16);
}

// XOR-swizzled LDS index (shorts) for 64x64 bf16 tiles w/ 128B rows.
// byteoff must be the un-swizzled byte offset within the row.
__device__ __forceinline__ int swzs(int row, int byteoff) {
    return (row * 128 + (byteoff ^ ((row & 7) << 4))) >> 1;
}

// ---------------------------------------------------------------------------
// Kernel 1: fused QKV projection.  C[M=4096][N=2048] = x @ [Wq | Wk | Wv]
// ---------------------------------------------------------------------------
__global__ __launch_bounds__(256) void gemm_qkv(
        const float* __restrict__ x, const float* __restrict__ Wq,
        const float* __restrict__ Wk, const float* __restrict__ Wv,
        float* __restrict__ q, float* __restrict__ k, float* __restrict__ v) {
    __shared__ float As[16][65];
    __shared__ float Bs[16][65];
    const int n0 = blockIdx.x * 64;
    const int m0 = blockIdx.y * 64;

    const float* W; int ldb, c0; float* out; int ldo, oc0;
    if (n0 < 1024)      { W = Wq; ldb = 1024; c0 = n0;        out = q; ldo = 1024; oc0 = n0; }
    else if (n0 < 1536) { W = Wk; ldb = 512;  c0 = n0 - 1024; out = k; ldo = 512;  oc0 = n0 - 1024; }
    else                { W = Wv; ldb = 512;  c0 = n0 - 1536; out = v; ldo = 512;  oc0 = n0 - 1536; }

    const int tid = threadIdx.x;
    const int tx = tid & 15, ty = tid >> 4;
    float acc[4][4] = {};

    for (int k0 = 0; k0 < DM; k0 += 16) {
        #pragma unroll
        for (int i = 0; i < 4; i++) {
            int e = tid + 256 * i;
            int mm = e >> 4, kk = e & 15;
            As[kk][mm] = x[(size_t)(m0 + mm) * DM + k0 + kk];
        }
        #pragma unroll
        for (int i = 0; i < 4; i++) {
            int e = tid + 256 * i;
            int kk = e >> 6, nn = e & 63;
            Bs[kk][nn] = W[(size_t)(k0 + kk) * ldb + c0 + nn];
        }
        __syncthreads();
        #pragma unroll
        for (int kk = 0; kk < 16; kk++) {
            float a[4], b[4];
            #pragma unroll
            for (int i = 0; i < 4; i++) a[i] = As[kk][ty * 4 + i];
            #pragma unroll
            for (int j = 0; j < 4; j++) b[j] = Bs[kk][tx * 4 + j];
            #pragma unroll
            for (int i = 0; i < 4; i++)
                #pragma unroll
                for (int j = 0; j < 4; j++)
                    acc[i][j] += a[i] * b[j];
        }
        __syncthreads();
    }
    #pragma unroll
    for (int i = 0; i < 4; i++)
        #pragma unroll
        for (int j = 0; j < 4; j++)
            out[(size_t)(m0 + ty * 4 + i) * ldo + oc0 + tx * 4 + j] = acc[i][j];
}

// ---------------------------------------------------------------------------
// Kernel 2: flash attention, bf16 MFMA (16x16x32).
// grid (S/64, B*QH), 256 threads = 4 waves; each wave owns 16 q-rows.
// K in LDS row-major [t][d] (XOR-swizzled); V in LDS transposed [d][t]
// (XOR-swizzled); P round-trips through per-wave LDS scratch.
// ---------------------------------------------------------------------------
__global__ __launch_bounds__(256) void flash_attn_mfma(
        const float* __restrict__ q, const float* __restrict__ kbuf,
        const float* __restrict__ vbuf, float* __restrict__ a_dot) {
    __shared__ __align__(16) short Klds[4096];   // [t=64][d=64] swizzled
    __shared__ __align__(16) short Vlds[4096];   // [d=64][t=64] swizzled
    __shared__ __align__(16) short Plds[4096];   // 4 waves x [q=16][t=64] swizzled

    const int r0 = blockIdx.x * 64;
    const int bh = blockIdx.y;
    const int b = bh >> 4, qh = bh & 15;
    const int kvh = qh >> 1;
    const int tid = threadIdx.x;
    const int lane = tid & 63, wv = tid >> 6;
    const int qr = lane & 15;        // A-frag row / B-frag col / P row
    const int kg = lane >> 4;        // k-group (0..3)
    const int st = tid & 63, dg = tid >> 6;  // staging: key index, d-group
    const float scale = 0.125f;

    // Q A-fragments in registers, scale folded in. chunk c covers d=[c*32, c*32+32)
    short8 qa[2];
    {
        const float* qp = q + (size_t)(b * SS + r0 + wv * 16 + qr) * DM + qh * DH + kg * 8;
        #pragma unroll
        for (int c = 0; c < 2; c++) {
            float4 f0 = *(const float4*)(qp + c * 32);
            float4 f1 = *(const float4*)(qp + c * 32 + 4);
            short8 t;
            t[0] = f2bf(f0.x * scale); t[1] = f2bf(f0.y * scale);
            t[2] = f2bf(f0.z * scale); t[3] = f2bf(f0.w * scale);
            t[4] = f2bf(f1.x * scale); t[5] = f2bf(f1.y * scale);
            t[6] = f2bf(f1.z * scale); t[7] = f2bf(f1.w * scale);
            qa[c] = t;
        }
    }

    f32x4 oacc[4];
    #pragma unroll
    for (int dt = 0; dt < 4; dt++) oacc[dt] = (f32x4){0.f, 0.f, 0.f, 0.f};
    float m_i[4], l_i[4];
    #pragma unroll
    for (int r = 0; r < 4; r++) { m_i[r] = -1e30f; l_i[r] = 0.0f; }

    short* Pw = Plds + wv * 1024;   // 16 rows x 64 t (128B rows)

    for (int t0 = 0; t0 < SS; t0 += 64) {
        // ---- stage K tile and V^T tile ----
        {
            const size_t gbase = (size_t)(b * SS + t0 + st) * KVD + kvh * DH + dg * 16;
            const float* kp = kbuf + gbase;
            const float* vp = vbuf + gbase;
            float4 k0 = *(const float4*)(kp);
            float4 k1 = *(const float4*)(kp + 4);
            float4 k2 = *(const float4*)(kp + 8);
            float4 k3 = *(const float4*)(kp + 12);
            short8 s0, s1;
            s0[0] = f2bf(k0.x); s0[1] = f2bf(k0.y); s0[2] = f2bf(k0.z); s0[3] = f2bf(k0.w);
            s0[4] = f2bf(k1.x); s0[5] = f2bf(k1.y); s0[6] = f2bf(k1.z); s0[7] = f2bf(k1.w);
            s1[0] = f2bf(k2.x); s1[1] = f2bf(k2.y); s1[2] = f2bf(k2.z); s1[3] = f2bf(k2.w);
            s1[4] = f2bf(k3.x); s1[5] = f2bf(k3.y); s1[6] = f2bf(k3.z); s1[7] = f2bf(k3.w);
            *(short8*)&Klds[swzs(st, dg * 32)]      = s0;
            *(short8*)&Klds[swzs(st, dg * 32 + 16)] = s1;

            float4 va[4];
            va[0] = *(const float4*)(vp);
            va[1] = *(const float4*)(vp + 4);
            va[2] = *(const float4*)(vp + 8);
            va[3] = *(const float4*)(vp + 12);
            #pragma unroll
            for (int c4 = 0; c4 < 4; c4++) {
                #pragma unroll
                for (int e = 0; e < 4; e++) {
                    int d = dg * 16 + c4 * 4 + e;
                    float val = (e == 0) ? va[c4].x : (e == 1) ? va[c4].y
                              : (e == 2) ? va[c4].z : va[c4].w;
                    Vlds[swzs(d, st * 2)] = f2bf(val);
                }
            }
        }
        __syncthreads();

        // ---- S = Q K^T : 4 t-tiles of 16, 2 d-chunks of 32 ----
        f32x4 sacc[4];
        #pragma unroll
        for (int j = 0; j < 4; j++) sacc[j] = (f32x4){0.f, 0.f, 0.f, 0.f};
        #pragma unroll
        for (int c = 0; c < 2; c++) {
            #pragma unroll
            for (int j = 0; j < 4; j++) {
                short8 kb = *(const short8*)&Klds[swzs(j * 16 + qr, kg * 16 + c * 64)];
                sacc[j] = __builtin_amdgcn_mfma_f32_16x16x32_bf16(qa[c], kb, sacc[j], 0, 0, 0);
            }
        }

        // ---- online softmax; P (bf16) to per-wave LDS ----
        #pragma unroll
        for (int r = 0; r < 4; r++) {
            float rm = fmaxf(fmaxf(sacc[0][r], sacc[1][r]), fmaxf(sacc[2][r], sacc[3][r]));
            rm = fmaxf(rm, __shfl_xor(rm, 1));
            rm = fmaxf(rm, __shfl_xor(rm, 2));
            rm = fmaxf(rm, __shfl_xor(rm, 4));
            rm = fmaxf(rm, __shfl_xor(rm, 8));
            float mn = fmaxf(m_i[r], rm);
            float resc = __expf(m_i[r] - mn);
            m_i[r] = mn;
            float rs = 0.0f;
            #pragma unroll
            for (int j = 0; j < 4; j++) {
                float p = __expf(sacc[j][r] - mn);
                rs += p;
                Pw[swzs(kg * 4 + r, (j * 16 + qr) * 2)] = f2bf(p);
            }
            rs += __shfl_xor(rs, 1);
            rs += __shfl_xor(rs, 2);
            rs += __shfl_xor(rs, 4);
            rs += __shfl_xor(rs, 8);
            l_i[r] = l_i[r] * resc + rs;
            #pragma unroll
            for (int dt = 0; dt < 4; dt++) oacc[dt][r] *= resc;
        }
        // P writes must land before A-frag reads (cross-lane within wave)
        asm volatile("s_waitcnt lgkmcnt(0)" ::: "memory");

        // ---- O += P V : A = P[16q][t], B = V[t][d] via V^T LDS ----
        #pragma unroll
        for (int c = 0; c < 2; c++) {
            short8 pa = *(const short8*)&Pw[swzs(qr, kg * 16 + c * 64)];
            #pragma unroll
            for (int dt = 0; dt < 4; dt++) {
                short8 vb = *(const short8*)&Vlds[swzs(dt * 16 + qr, kg * 16 + c * 64)];
                oacc[dt] = __builtin_amdgcn_mfma_f32_16x16x32_bf16(pa, vb, oacc[dt], 0, 0, 0);
            }
        }
        __syncthreads();
    }

    #pragma unroll
    for (int r = 0; r < 4; r++) {
        float inv = 1.0f / l_i[r];
        #pragma unroll
        for (int dt = 0; dt < 4; dt++)
            a_dot[(size_t)(b * SS + r0 + wv * 16 + kg * 4 + r) * DM + qh * DH + dt * 16 + qr]
                = oacc[dt][r] * inv;
    }
}

// ---------------------------------------------------------------------------
// Kernel 3: per-row dot of elu(src_row) with norm vector.
// ---------------------------------------------------------------------------
__global__ __launch_bounds__(256) void row_dot(
        const float* __restrict__ src, const float* __restrict__ norm,
        float* __restrict__ den, int nrows) {
    const int wave = threadIdx.x >> 6, lane = threadIdx.x & 63;
    const int row = blockIdx.x * 4 + wave;
    if (row >= nrows) return;
    const float* p = src + (size_t)row * KVD;
    float s = 0.0f;
    #pragma unroll
    for (int j = 0; j < 8; j++) {
        int c = lane + 64 * j;
        s += elu_f(p[c]) * norm[c];
    }
    #pragma unroll
    for (int off = 32; off >= 1; off >>= 1) s += __shfl_xor(s, off);
    if (lane == 0) den[row] = s;
}

// ---------------------------------------------------------------------------
// Kernel 4: a_mem GEMM + gated fusion epilogue (writes final `out`).
// ---------------------------------------------------------------------------
__global__ __launch_bounds__(256) void gemm_amem(
        const float* __restrict__ q, const float* __restrict__ memory,
        const float* __restrict__ a_dot, const float* __restrict__ den_q,
        const float* __restrict__ mw, float* __restrict__ out) {
    __shared__ float As[16][65];
    __shared__ float Bs[16][65];
    const int n0 = blockIdx.x * 64;
    const int m0 = blockIdx.y * 64;
    const int tid = threadIdx.x;
    const int tx = tid & 15, ty = tid >> 4;
    const float w = 1.0f / (1.0f + __expf(-mw[0]));
    float acc[4][4] = {};

    for (int k0 = 0; k0 < KVD; k0 += 16) {
        #pragma unroll
        for (int i = 0; i < 4; i++) {
            int e = tid + 256 * i;
            int mm = e >> 4, kk = e & 15;
            As[kk][mm] = elu_f(q[(size_t)(m0 + mm) * KVD + k0 + kk]);
        }
        #pragma unroll
        for (int i = 0; i < 4; i++) {
            int e = tid + 256 * i;
            int kk = e >> 6, nn = e & 63;
            Bs[kk][nn] = memory[(size_t)(k0 + kk) * KVD + n0 + nn];
        }
        __syncthreads();
        #pragma unroll
        for (int kk = 0; kk < 16; kk++) {
            float a[4], b[4];
            #pragma unroll
            for (int i = 0; i < 4; i++) a[i] = As[kk][ty * 4 + i];
            #pragma unroll
            for (int j = 0; j < 4; j++) b[j] = Bs[kk][tx * 4 + j];
            #pragma unroll
            for (int i = 0; i < 4; i++)
                #pragma unroll
                for (int j = 0; j < 4; j++)
                    acc[i][j] += a[i] * b[j];
        }
        __syncthreads();
    }
    #pragma unroll
    for (int i = 0; i < 4; i++) {
        int m = m0 + ty * 4 + i;
        float invden = 1.0f / den_q[m];
        #pragma unroll
        for (int j = 0; j < 4; j++) {
            size_t fo = (size_t)m * KVD + n0 + tx * 4 + j;
            out[fo] = a_dot[fo] * (1.0f - w) + acc[i][j] * invden * w;
        }
    }
}

// ---------------------------------------------------------------------------
// Kernel 5: u = v - (elu(k) @ memory) / den_k.
// ---------------------------------------------------------------------------
__global__ __launch_bounds__(256) void gemm_u(
        const float* __restrict__ kbuf, const float* __restrict__ memory,
        const float* __restrict__ vbuf, const float* __restrict__ den_k,
        float* __restrict__ u) {
    __shared__ float As[16][65];
    __shared__ float Bs[16][65];
    const int n0 = blockIdx.x * 64;
    const int m0 = blockIdx.y * 64;
    const int tid = threadIdx.x;
    const int tx = tid & 15, ty = tid >> 4;
    float acc[4][4] = {};

    for (int k0 = 0; k0 < KVD; k0 += 16) {
        #pragma unroll
        for (int i = 0; i < 4; i++) {
            int e = tid + 256 * i;
            int mm = e >> 4, kk = e & 15;
            As[kk][mm] = elu_f(kbuf[(size_t)(m0 + mm) * KVD + k0 + kk]);
        }
        #pragma unroll
        for (int i = 0; i < 4; i++) {
            int e = tid + 256 * i;
            int kk = e >> 6, nn = e & 63;
            Bs[kk][nn] = memory[(size_t)(k0 + kk) * KVD + n0 + nn];
        }
        __syncthreads();
        #pragma unroll
        for (int kk = 0; kk < 16; kk++) {
            float a[4], b[4];
            #pragma unroll
            for (int i = 0; i < 4; i++) a[i] = As[kk][ty * 4 + i];
            #pragma unroll
            for (int j = 0; j < 4; j++) b[j] = Bs[kk][tx * 4 + j];
            #pragma unroll
            for (int i = 0; i < 4; i++)
                #pragma unroll
                for (int j = 0; j < 4; j++)
                    acc[i][j] += a[i] * b[j];
        }
        __syncthreads();
    }
    #pragma unroll
    for (int i = 0; i < 4; i++) {
        int m = m0 + ty * 4 + i;
        float invden = 1.0f / den_k[m];
        #pragma unroll
        for (int j = 0; j < 4; j++) {
            size_t fo = (size_t)m * KVD + n0 + tx * 4 + j;
            u[fo] = vbuf[fo] - acc[i][j] * invden;
        }
    }
}

// ---------------------------------------------------------------------------
// Kernel 6/7: column sums of elu(k) -> new_memory_norm
// ---------------------------------------------------------------------------
__global__ __launch_bounds__(256) void colsum_part(
        const float* __restrict__ kbuf, float* __restrict__ part) {
    const int blk = blockIdx.x;
    const int tid = threadIdx.x;
    float a0 = 0.0f, a1 = 0.0f;
    for (int r = 0; r < 128; r++) {
        size_t row = (size_t)(blk * 128 + r) * KVD;
        a0 += elu_f(kbuf[row + tid]);
        a1 += elu_f(kbuf[row + tid + 256]);
    }
    part[blk * KVD + tid] = a0;
    part[blk * KVD + tid + 256] = a1;
}

__global__ __launch_bounds__(256) void colsum_final(
        const float* __restrict__ part, const float* __restrict__ mnorm,
        float* __restrict__ out_norm) {
    const int c = blockIdx.x * 256 + threadIdx.x;
    float s = mnorm[c];
    for (int b = 0; b < 32; b++) s += part[b * KVD + c];
    out_norm[c] = s;
}

// ---------------------------------------------------------------------------
// Kernel 8: split-K delta GEMM + finalize
// ---------------------------------------------------------------------------
__global__ __launch_bounds__(256) void gemm_delta(
        const float* __restrict__ kbuf, const float* __restrict__ u,
        float* __restrict__ part) {
    __shared__ float As[16][65];
    __shared__ float Bs[16][65];
    const int j0 = blockIdx.x * 64;
    const int i0 = blockIdx.y * 64;
    const int kc = blockIdx.z;
    const int tid = threadIdx.x;
    const int tx = tid & 15, ty = tid >> 4;
    float acc[4][4] = {};

    for (int s0 = kc * 512; s0 < kc * 512 + 512; s0 += 16) {
        #pragma unroll
        for (int i = 0; i < 4; i++) {
            int e = tid + 256 * i;
            int ss = e >> 6, ii = e & 63;
            As[ss][ii] = elu_f(kbuf[(size_t)(s0 + ss) * KVD + i0 + ii]);
        }
        #pragma unroll
        for (int i = 0; i < 4; i++) {
            int e = tid + 256 * i;
            int ss = e >> 6, jj = e & 63;
            Bs[ss][jj] = u[(size_t)(s0 + ss) * KVD + j0 + jj];
        }
        __syncthreads();
        #pragma unroll
        for (int ss = 0; ss < 16; ss++) {
            float a[4], b[4];
            #pragma unroll
            for (int i = 0; i < 4; i++) a[i] = As[ss][ty * 4 + i];
            #pragma unroll
            for (int j = 0; j < 4; j++) b[j] = Bs[ss][tx * 4 + j];
            #pragma unroll
            for (int i = 0; i < 4; i++)
                #pragma unroll
                for (int j = 0; j < 4; j++)
                    acc[i][j] += a[i] * b[j];
        }
        __syncthreads();
    }
    #pragma unroll
    for (int i = 0; i < 4; i++)
        #pragma unroll
        for (int j = 0; j < 4; j++)
            part[(size_t)kc * (KVD * KVD) + (size_t)(i0 + ty * 4 + i) * KVD + j0 + tx * 4 + j]
                = acc[i][j];
}

__global__ __launch_bounds__(256) void delta_final(
        const float* __restrict__ part, const float* __restrict__ memory,
        float* __restrict__ out_mem) {
    const int idx = blockIdx.x * 256 + threadIdx.x;
    float s = memory[idx];
    #pragma unroll
    for (int kc = 0; kc < 8; kc++) s += part[(size_t)kc * (KVD * KVD) + idx];
    out_mem[idx] = s;
}

// ---------------------------------------------------------------------------
extern "C" void kernel_launch(void* const* d_in, const int* in_sizes, int n_in,
                              void* d_out, int out_size, void* d_ws, size_t ws_size,
                              hipStream_t stream) {
    const float* x      = (const float*)d_in[0];
    const float* Wq     = (const float*)d_in[1];
    const float* Wk     = (const float*)d_in[2];
    const float* Wv     = (const float*)d_in[3];
    const float* memory = (const float*)d_in[4];
    const float* mnorm  = (const float*)d_in[5];
    const float* mw     = (const float*)d_in[6];

    float* out_f   = (float*)d_out;
    float* out_mem = out_f + (size_t)MROWS * DM;
    float* out_nrm = out_mem + (size_t)KVD * KVD;

    float* ws = (float*)d_ws;
    float* q      = ws;
    float* kbuf   = q + (size_t)MROWS * DM;
    float* vbuf   = kbuf + (size_t)MROWS * KVD;
    float* a_dot  = vbuf + (size_t)MROWS * KVD;
    float* u      = a_dot + (size_t)MROWS * DM;
    float* den_q  = u + (size_t)MROWS * KVD;
    float* den_k  = den_q + 8192;
    float* cspart = den_k + 4096;
    float* dpart  = q;  // q dead after gemm_amem; reuse for delta partials

    gemm_qkv<<<dim3(32, 64), 256, 0, stream>>>(x, Wq, Wk, Wv, q, kbuf, vbuf);
    flash_attn_mfma<<<dim3(32, 32), 256, 0, stream>>>(q, kbuf, vbuf, a_dot);
    row_dot<<<2048, 256, 0, stream>>>(q, mnorm, den_q, 8192);
    row_dot<<<1024, 256, 0, stream>>>(kbuf, mnorm, den_k, 4096);
    gemm_amem<<<dim3(8, 128), 256, 0, stream>>>(q, memory, a_dot, den_q, mw, out_f);
    colsum_part<<<32, 256, 0, stream>>>(kbuf, cspart);
    colsum_final<<<2, 256, 0, stream>>>(cspart, mnorm, out_nrm);
    gemm_u<<<dim3(8, 64), 256, 0, stream>>>(kbuf, memory, vbuf, den_k, u);
    gemm_delta<<<dim3(8, 8, 8), 256, 0, stream>>>(kbuf, u, dpart);
    delta_final<<<1024, 256, 0, stream>>>(dpart, memory, out_mem);
}

// Round 3
// 233.405 us; speedup vs baseline: 7.1364x; 3.1254x over previous
//
#include <hip/hip_runtime.h>
#include <hip/hip_bf16.h>

// Problem constants
#define BB 2
#define SS 2048
#define DM 1024
#define KVD 512
#define NH 8
#define NQ 2
#define QH 16
#define DH 64
#define MROWS 4096   // B*S

typedef float f32x4 __attribute__((ext_vector_type(4)));
typedef short short8 __attribute__((ext_vector_type(8)));
typedef short short4v __attribute__((ext_vector_type(4)));

__device__ __forceinline__ float elu_f(float x) {
    return x > 0.0f ? x : (__expf(x) - 1.0f);
}

// float -> bf16 (round to nearest even), raw short
__device__ __forceinline__ short f2bf(float f) {
    union { float f; unsigned u; } v; v.f = f;
    unsigned r = v.u + 0x7FFFu + ((v.u >> 16) & 1u);
    return (short)(r >> 16);
}
__device__ __forceinline__ float bf2f(short s) {
    union { unsigned u; float f; } v;
    v.u = ((unsigned)(unsigned short)s) << 16;
    return v.f;
}

// XOR-swizzled LDS index (in shorts) for 128B rows: bijective 16B-slot permute.
__device__ __forceinline__ int swzs(int row, int byteoff) {
    return (row * 128 + (byteoff ^ ((row & 7) << 4))) >> 1;
}

// ---------------------------------------------------------------------------
// Shared MFMA-GEMM building blocks: 128x128 tile, BK=64, 256 thr = 4 waves.
// Both operands K-major (A[m][k], Bt[n][k]), bf16, swizzled LDS.
// ---------------------------------------------------------------------------
template<bool ELU>
__device__ __forceinline__ void stage_tile(const short* __restrict__ src, int ld,
                                           int row0, int k0,
                                           short* __restrict__ L, int tid) {
    #pragma unroll
    for (int i = 0; i < 4; i++) {
        int idx = tid + i * 256;
        int r = idx >> 3, c16 = idx & 7;
        short8 s = *(const short8*)&src[(size_t)(row0 + r) * ld + k0 + c16 * 8];
        if (ELU) {
            #pragma unroll
            for (int j = 0; j < 8; j++) s[j] = f2bf(elu_f(bf2f(s[j])));
        }
        *(short8*)&L[swzs(r, c16 * 16)] = s;
    }
}

__device__ __forceinline__ void mma_tile(const short* __restrict__ Als,
                                         const short* __restrict__ Bls,
                                         int mb, int nb, int qr, int kg,
                                         f32x4 acc[4][4]) {
    #pragma unroll
    for (int kc = 0; kc < 2; kc++) {
        short8 af[4], bg[4];
        #pragma unroll
        for (int mi = 0; mi < 4; mi++)
            af[mi] = *(const short8*)&Als[swzs(mb + mi * 16 + qr, kc * 64 + kg * 16)];
        #pragma unroll
        for (int ni = 0; ni < 4; ni++)
            bg[ni] = *(const short8*)&Bls[swzs(nb + ni * 16 + qr, kc * 64 + kg * 16)];
        #pragma unroll
        for (int mi = 0; mi < 4; mi++)
            #pragma unroll
            for (int ni = 0; ni < 4; ni++)
                acc[mi][ni] = __builtin_amdgcn_mfma_f32_16x16x32_bf16(
                    af[mi], bg[ni], acc[mi][ni], 0, 0, 0);
    }
}

// ---------------------------------------------------------------------------
// Pre-passes: convert / transpose to bf16 K-major operands
// ---------------------------------------------------------------------------
__global__ __launch_bounds__(256) void convert_x(
        const float* __restrict__ x, short* __restrict__ xb) {
    int i = (blockIdx.x * 256 + threadIdx.x) * 8;
    float4 a = *(const float4*)&x[i];
    float4 b = *(const float4*)&x[i + 4];
    short8 s;
    s[0] = f2bf(a.x); s[1] = f2bf(a.y); s[2] = f2bf(a.z); s[3] = f2bf(a.w);
    s[4] = f2bf(b.x); s[5] = f2bf(b.y); s[6] = f2bf(b.z); s[7] = f2bf(b.w);
    *(short8*)&xb[i] = s;
}

// Wt[n][k] = W[k][n], fused [Wq|Wk|Wv] columns as rows. 64x64 tiles.
__global__ __launch_bounds__(256) void transpose_w(
        const float* __restrict__ Wq, const float* __restrict__ Wk,
        const float* __restrict__ Wv, short* __restrict__ wtb) {
    __shared__ float Ts[64][65];
    const int k0 = blockIdx.x * 64, n0 = blockIdx.y * 64;
    const float* W; int ld, c0;
    if (n0 < 1024)      { W = Wq; ld = 1024; c0 = n0; }
    else if (n0 < 1536) { W = Wk; ld = 512;  c0 = n0 - 1024; }
    else                { W = Wv; ld = 512;  c0 = n0 - 1536; }
    const int tid = threadIdx.x;
    #pragma unroll
    for (int i = 0; i < 16; i++) {
        int e = tid + 256 * i;
        int kk = e >> 6, nn = e & 63;
        Ts[nn][kk] = W[(size_t)(k0 + kk) * ld + c0 + nn];
    }
    __syncthreads();
    #pragma unroll
    for (int i = 0; i < 16; i++) {
        int e = tid + 256 * i;
        int nn = e >> 6, kk = e & 63;
        wtb[(size_t)(n0 + nn) * 1024 + k0 + kk] = f2bf(Ts[nn][kk]);
    }
}

__global__ __launch_bounds__(256) void transpose_mem(
        const float* __restrict__ m, short* __restrict__ memtb) {
    __shared__ float Ts[64][65];
    const int k0 = blockIdx.x * 64, n0 = blockIdx.y * 64;
    const int tid = threadIdx.x;
    #pragma unroll
    for (int i = 0; i < 16; i++) {
        int e = tid + 256 * i;
        int kk = e >> 6, nn = e & 63;
        Ts[nn][kk] = m[(size_t)(k0 + kk) * 512 + n0 + nn];
    }
    __syncthreads();
    #pragma unroll
    for (int i = 0; i < 16; i++) {
        int e = tid + 256 * i;
        int nn = e >> 6, kk = e & 63;
        memtb[(size_t)(n0 + nn) * 512 + k0 + kk] = f2bf(Ts[nn][kk]);
    }
}

// keluT[i][s] = bf16(elu(k[s][i]))
__global__ __launch_bounds__(256) void transpose_kelu(
        const short* __restrict__ kb, short* __restrict__ keluT) {
    __shared__ short Ts[64][65];
    const int s0 = blockIdx.x * 64, i0 = blockIdx.y * 64;
    const int tid = threadIdx.x;
    #pragma unroll
    for (int i = 0; i < 16; i++) {
        int e = tid + 256 * i;
        int ss = e >> 6, ii = e & 63;
        Ts[ii][ss] = kb[(size_t)(s0 + ss) * 512 + i0 + ii];
    }
    __syncthreads();
    #pragma unroll
    for (int i = 0; i < 16; i++) {
        int e = tid + 256 * i;
        int ii = e >> 6, ss = e & 63;
        keluT[(size_t)(i0 + ii) * 4096 + s0 + ss] = f2bf(elu_f(bf2f(Ts[ii][ss])));
    }
}

// ---------------------------------------------------------------------------
// GEMM 1: QKV. C[4096][2048] = xb @ Wt^T -> q/k/v bf16
// ---------------------------------------------------------------------------
__global__ __launch_bounds__(256) void gemm_qkv_mfma(
        const short* __restrict__ xb, const short* __restrict__ wtb,
        short* __restrict__ q, short* __restrict__ k, short* __restrict__ v) {
    __shared__ short Als[8192];
    __shared__ short Bls[8192];
    const int n0 = blockIdx.x * 128, m0 = blockIdx.y * 128;
    const int tid = threadIdx.x, lane = tid & 63, wv = tid >> 6;
    const int qr = lane & 15, kg = lane >> 4;
    const int mb = (wv >> 1) * 64, nb = (wv & 1) * 64;

    f32x4 acc[4][4];
    #pragma unroll
    for (int i = 0; i < 4; i++)
        #pragma unroll
        for (int j = 0; j < 4; j++) acc[i][j] = (f32x4){0.f, 0.f, 0.f, 0.f};

    for (int kt = 0; kt < 16; kt++) {
        stage_tile<false>(xb, 1024, m0, kt * 64, Als, tid);
        stage_tile<false>(wtb, 1024, n0, kt * 64, Bls, tid);
        __syncthreads();
        mma_tile(Als, Bls, mb, nb, qr, kg, acc);
        __syncthreads();
    }

    short* dst; int ldo, c0;
    if (n0 < 1024)      { dst = q; ldo = 1024; c0 = n0; }
    else if (n0 < 1536) { dst = k; ldo = 512;  c0 = n0 - 1024; }
    else                { dst = v; ldo = 512;  c0 = n0 - 1536; }
    #pragma unroll
    for (int mi = 0; mi < 4; mi++)
        #pragma unroll
        for (int ni = 0; ni < 4; ni++)
            #pragma unroll
            for (int r = 0; r < 4; r++) {
                int gr = m0 + mb + mi * 16 + kg * 4 + r;
                int gc = c0 + nb + ni * 16 + qr;
                dst[(size_t)gr * ldo + gc] = f2bf(acc[mi][ni][r]);
            }
}

// ---------------------------------------------------------------------------
// GEMM 2: a_mem + gated fusion.  A = elu(q)[8192][512], B = memT. out fp32.
// ---------------------------------------------------------------------------
__global__ __launch_bounds__(256) void gemm_amem_mfma(
        const short* __restrict__ qb, const short* __restrict__ memtb,
        const float* __restrict__ a_dot, const float* __restrict__ den_q,
        const float* __restrict__ mw, float* __restrict__ out) {
    __shared__ short Als[8192];
    __shared__ short Bls[8192];
    const int n0 = blockIdx.x * 128, m0 = blockIdx.y * 128;
    const int tid = threadIdx.x, lane = tid & 63, wv = tid >> 6;
    const int qr = lane & 15, kg = lane >> 4;
    const int mb = (wv >> 1) * 64, nb = (wv & 1) * 64;
    const float wgt = 1.0f / (1.0f + __expf(-mw[0]));

    f32x4 acc[4][4];
    #pragma unroll
    for (int i = 0; i < 4; i++)
        #pragma unroll
        for (int j = 0; j < 4; j++) acc[i][j] = (f32x4){0.f, 0.f, 0.f, 0.f};

    for (int kt = 0; kt < 8; kt++) {
        stage_tile<true>(qb, 512, m0, kt * 64, Als, tid);
        stage_tile<false>(memtb, 512, n0, kt * 64, Bls, tid);
        __syncthreads();
        mma_tile(Als, Bls, mb, nb, qr, kg, acc);
        __syncthreads();
    }

    #pragma unroll
    for (int mi = 0; mi < 4; mi++) {
        int gr0 = m0 + mb + mi * 16 + kg * 4;
        float invd[4];
        #pragma unroll
        for (int r = 0; r < 4; r++) invd[r] = 1.0f / den_q[gr0 + r];
        #pragma unroll
        for (int ni = 0; ni < 4; ni++) {
            int gc = n0 + nb + ni * 16 + qr;
            #pragma unroll
            for (int r = 0; r < 4; r++) {
                size_t fo = (size_t)(gr0 + r) * 512 + gc;
                out[fo] = a_dot[fo] * (1.0f - wgt) + acc[mi][ni][r] * invd[r] * wgt;
            }
        }
    }
}

// ---------------------------------------------------------------------------
// GEMM 3: u = v - (elu(k) @ memory)/den_k, written TRANSPOSED: uT[n][m] bf16
// ---------------------------------------------------------------------------
__global__ __launch_bounds__(256) void gemm_u_mfma(
        const short* __restrict__ kb, const short* __restrict__ memtb,
        const short* __restrict__ vb, const float* __restrict__ den_k,
        short* __restrict__ uT) {
    __shared__ short Als[8192];
    __shared__ short Bls[8192];
    const int n0 = blockIdx.x * 128, m0 = blockIdx.y * 128;
    const int tid = threadIdx.x, lane = tid & 63, wv = tid >> 6;
    const int qr = lane & 15, kg = lane >> 4;
    const int mb = (wv >> 1) * 64, nb = (wv & 1) * 64;

    f32x4 acc[4][4];
    #pragma unroll
    for (int i = 0; i < 4; i++)
        #pragma unroll
        for (int j = 0; j < 4; j++) acc[i][j] = (f32x4){0.f, 0.f, 0.f, 0.f};

    for (int kt = 0; kt < 8; kt++) {
        stage_tile<true>(kb, 512, m0, kt * 64, Als, tid);
        stage_tile<false>(memtb, 512, n0, kt * 64, Bls, tid);
        __syncthreads();
        mma_tile(Als, Bls, mb, nb, qr, kg, acc);
        __syncthreads();
    }

    #pragma unroll
    for (int mi = 0; mi < 4; mi++) {
        int gr0 = m0 + mb + mi * 16 + kg * 4;
        float invd[4];
        #pragma unroll
        for (int r = 0; r < 4; r++) invd[r] = 1.0f / den_k[gr0 + r];
        #pragma unroll
        for (int ni = 0; ni < 4; ni++) {
            int gc = n0 + nb + ni * 16 + qr;
            short4v st;
            #pragma unroll
            for (int r = 0; r < 4; r++)
                st[r] = f2bf(bf2f(vb[(size_t)(gr0 + r) * 512 + gc])
                             - acc[mi][ni][r] * invd[r]);
            *(short4v*)&uT[(size_t)gc * 4096 + gr0] = st;
        }
    }
}

// ---------------------------------------------------------------------------
// GEMM 4: delta, split-K=16. C[i][j] += sum_s keluT[i][s]*uT[j][s]
// ---------------------------------------------------------------------------
__global__ __launch_bounds__(256) void gemm_delta_mfma(
        const short* __restrict__ keluT, const short* __restrict__ uT,
        float* __restrict__ dpart) {
    __shared__ short Als[8192];
    __shared__ short Bls[8192];
    const int j0 = blockIdx.x * 128, i0 = blockIdx.y * 128;
    const int kcz = blockIdx.z;
    const int tid = threadIdx.x, lane = tid & 63, wv = tid >> 6;
    const int qr = lane & 15, kg = lane >> 4;
    const int mb = (wv >> 1) * 64, nb = (wv & 1) * 64;

    f32x4 acc[4][4];
    #pragma unroll
    for (int i = 0; i < 4; i++)
        #pragma unroll
        for (int j = 0; j < 4; j++) acc[i][j] = (f32x4){0.f, 0.f, 0.f, 0.f};

    for (int kt = 0; kt < 4; kt++) {
        int k0 = kcz * 256 + kt * 64;
        stage_tile<false>(keluT, 4096, i0, k0, Als, tid);
        stage_tile<false>(uT, 4096, j0, k0, Bls, tid);
        __syncthreads();
        mma_tile(Als, Bls, mb, nb, qr, kg, acc);
        __syncthreads();
    }

    #pragma unroll
    for (int mi = 0; mi < 4; mi++)
        #pragma unroll
        for (int ni = 0; ni < 4; ni++)
            #pragma unroll
            for (int r = 0; r < 4; r++) {
                int gr = i0 + mb + mi * 16 + kg * 4 + r;
                int gc = j0 + nb + ni * 16 + qr;
                dpart[(size_t)kcz * (KVD * KVD) + (size_t)gr * 512 + gc] = acc[mi][ni][r];
            }
}

__global__ __launch_bounds__(256) void delta_final(
        const float* __restrict__ part, const float* __restrict__ memory,
        float* __restrict__ out_mem) {
    const int idx = blockIdx.x * 256 + threadIdx.x;
    float s = memory[idx];
    #pragma unroll
    for (int kc = 0; kc < 16; kc++) s += part[(size_t)kc * (KVD * KVD) + idx];
    out_mem[idx] = s;
}

// ---------------------------------------------------------------------------
// Flash attention, bf16 MFMA, bf16 inputs. (Round-2 verified structure.)
// ---------------------------------------------------------------------------
__global__ __launch_bounds__(256) void flash_attn_mfma(
        const short* __restrict__ qb, const short* __restrict__ kb,
        const short* __restrict__ vb, float* __restrict__ a_dot) {
    __shared__ __align__(16) short Klds[4096];   // [t=64][d=64] swizzled
    __shared__ __align__(16) short Vlds[4096];   // [d=64][t=64] swizzled
    __shared__ __align__(16) short Plds[4096];   // 4 waves x [q=16][t=64]

    const int r0 = blockIdx.x * 64;
    const int bh = blockIdx.y;
    const int b = bh >> 4, qh = bh & 15;
    const int kvh = qh >> 1;
    const int tid = threadIdx.x;
    const int lane = tid & 63, wv = tid >> 6;
    const int qr = lane & 15;
    const int kg = lane >> 4;
    const int st = tid & 63, dg = tid >> 6;
    const float scale = 0.125f;

    short8 qa[2];
    {
        const short* qp = qb + (size_t)(b * SS + r0 + wv * 16 + qr) * DM + qh * DH;
        qa[0] = *(const short8*)&qp[kg * 8];
        qa[1] = *(const short8*)&qp[32 + kg * 8];
    }

    f32x4 oacc[4];
    #pragma unroll
    for (int dt = 0; dt < 4; dt++) oacc[dt] = (f32x4){0.f, 0.f, 0.f, 0.f};
    float m_i[4], l_i[4];
    #pragma unroll
    for (int r = 0; r < 4; r++) { m_i[r] = -1e30f; l_i[r] = 0.0f; }

    short* Pw = Plds + wv * 1024;

    for (int t0 = 0; t0 < SS; t0 += 64) {
        {
            const size_t gbase = (size_t)(b * SS + t0 + st) * KVD + kvh * DH + dg * 16;
            const short* kp = kb + gbase;
            const short* vp = vb + gbase;
            *(short8*)&Klds[swzs(st, dg * 32)]      = *(const short8*)kp;
            *(short8*)&Klds[swzs(st, dg * 32 + 16)] = *(const short8*)&kp[8];
            short8 v0 = *(const short8*)vp;
            short8 v1 = *(const short8*)&vp[8];
            #pragma unroll
            for (int e = 0; e < 8; e++) Vlds[swzs(dg * 16 + e, st * 2)] = v0[e];
            #pragma unroll
            for (int e = 0; e < 8; e++) Vlds[swzs(dg * 16 + 8 + e, st * 2)] = v1[e];
        }
        __syncthreads();

        // S = Q K^T
        f32x4 sacc[4];
        #pragma unroll
        for (int j = 0; j < 4; j++) sacc[j] = (f32x4){0.f, 0.f, 0.f, 0.f};
        #pragma unroll
        for (int c = 0; c < 2; c++) {
            #pragma unroll
            for (int j = 0; j < 4; j++) {
                short8 kf = *(const short8*)&Klds[swzs(j * 16 + qr, kg * 16 + c * 64)];
                sacc[j] = __builtin_amdgcn_mfma_f32_16x16x32_bf16(qa[c], kf, sacc[j], 0, 0, 0);
            }
        }

        // online softmax (scale applied to scores here)
        #pragma unroll
        for (int r = 0; r < 4; r++) {
            float s0 = sacc[0][r] * scale, s1 = sacc[1][r] * scale;
            float s2 = sacc[2][r] * scale, s3 = sacc[3][r] * scale;
            float rm = fmaxf(fmaxf(s0, s1), fmaxf(s2, s3));
            rm = fmaxf(rm, __shfl_xor(rm, 1));
            rm = fmaxf(rm, __shfl_xor(rm, 2));
            rm = fmaxf(rm, __shfl_xor(rm, 4));
            rm = fmaxf(rm, __shfl_xor(rm, 8));
            float mn = fmaxf(m_i[r], rm);
            float resc = __expf(m_i[r] - mn);
            m_i[r] = mn;
            float p0 = __expf(s0 - mn), p1 = __expf(s1 - mn);
            float p2 = __expf(s2 - mn), p3 = __expf(s3 - mn);
            Pw[swzs(kg * 4 + r, (0 * 16 + qr) * 2)] = f2bf(p0);
            Pw[swzs(kg * 4 + r, (1 * 16 + qr) * 2)] = f2bf(p1);
            Pw[swzs(kg * 4 + r, (2 * 16 + qr) * 2)] = f2bf(p2);
            Pw[swzs(kg * 4 + r, (3 * 16 + qr) * 2)] = f2bf(p3);
            float rs = p0 + p1 + p2 + p3;
            rs += __shfl_xor(rs, 1);
            rs += __shfl_xor(rs, 2);
            rs += __shfl_xor(rs, 4);
            rs += __shfl_xor(rs, 8);
            l_i[r] = l_i[r] * resc + rs;
            #pragma unroll
            for (int dt = 0; dt < 4; dt++) oacc[dt][r] *= resc;
        }
        asm volatile("s_waitcnt lgkmcnt(0)" ::: "memory");
        __builtin_amdgcn_sched_barrier(0);

        // O += P V
        #pragma unroll
        for (int c = 0; c < 2; c++) {
            short8 pa = *(const short8*)&Pw[swzs(qr, kg * 16 + c * 64)];
            #pragma unroll
            for (int dt = 0; dt < 4; dt++) {
                short8 vf = *(const short8*)&Vlds[swzs(dt * 16 + qr, kg * 16 + c * 64)];
                oacc[dt] = __builtin_amdgcn_mfma_f32_16x16x32_bf16(pa, vf, oacc[dt], 0, 0, 0);
            }
        }
        __syncthreads();
    }

    #pragma unroll
    for (int r = 0; r < 4; r++) {
        float inv = 1.0f / l_i[r];
        #pragma unroll
        for (int dt = 0; dt < 4; dt++)
            a_dot[(size_t)(b * SS + r0 + wv * 16 + kg * 4 + r) * DM + qh * DH + dt * 16 + qr]
                = oacc[dt][r] * inv;
    }
}

// ---------------------------------------------------------------------------
// Small memory-bound kernels (bf16 inputs)
// ---------------------------------------------------------------------------
__global__ __launch_bounds__(256) void row_dot_b16(
        const short* __restrict__ src, const float* __restrict__ norm,
        float* __restrict__ den, int nrows) {
    const int wavei = threadIdx.x >> 6, lane = threadIdx.x & 63;
    const int row = blockIdx.x * 4 + wavei;
    if (row >= nrows) return;
    short8 v = *(const short8*)&src[(size_t)row * 512 + lane * 8];
    float s = 0.0f;
    #pragma unroll
    for (int j = 0; j < 8; j++) s += elu_f(bf2f(v[j])) * norm[lane * 8 + j];
    #pragma unroll
    for (int off = 32; off >= 1; off >>= 1) s += __shfl_xor(s, off);
    if (lane == 0) den[row] = s;
}

__global__ __launch_bounds__(256) void colsum_rows(
        const short* __restrict__ keluT, const float* __restrict__ mnorm,
        float* __restrict__ out_norm) {
    const int wavei = threadIdx.x >> 6, lane = threadIdx.x & 63;
    const int row = blockIdx.x * 4 + wavei;   // 512 rows
    float s = 0.0f;
    #pragma unroll
    for (int j = 0; j < 8; j++) {
        short8 v = *(const short8*)&keluT[(size_t)row * 4096 + j * 512 + lane * 8];
        #pragma unroll
        for (int e = 0; e < 8; e++) s += bf2f(v[e]);
    }
    #pragma unroll
    for (int off = 32; off >= 1; off >>= 1) s += __shfl_xor(s, off);
    if (lane == 0) out_norm[row] = mnorm[row] + s;
}

// ---------------------------------------------------------------------------
extern "C" void kernel_launch(void* const* d_in, const int* in_sizes, int n_in,
                              void* d_out, int out_size, void* d_ws, size_t ws_size,
                              hipStream_t stream) {
    const float* x      = (const float*)d_in[0];
    const float* Wq     = (const float*)d_in[1];
    const float* Wk     = (const float*)d_in[2];
    const float* Wv     = (const float*)d_in[3];
    const float* memory = (const float*)d_in[4];
    const float* mnorm  = (const float*)d_in[5];
    const float* mw     = (const float*)d_in[6];

    float* out_f   = (float*)d_out;                 // 4096x1024
    float* out_mem = out_f + (size_t)MROWS * DM;    // 512x512
    float* out_nrm = out_mem + (size_t)KVD * KVD;   // 512

    // Workspace layout (bytes ~52.6 MB). dpart aliases xb..q (dead by then).
    short* xb    = (short*)d_ws;                    // 4M shorts
    short* wtb   = xb + 4194304;                    // 2M
    short* memtb = wtb + 2097152;                   // 256K
    short* qb    = memtb + 262144;                  // 4M
    short* kbuf  = qb + 4194304;                    // 2M
    short* vbuf  = kbuf + 2097152;                  // 2M
    float* a_dot = (float*)(vbuf + 2097152);        // 4M floats
    short* keluT = (short*)(a_dot + 4194304);       // 2M
    short* uT    = keluT + 2097152;                 // 2M
    float* den_q = (float*)(uT + 2097152);          // 8192
    float* den_k = den_q + 8192;                    // 4096
    float* dpart = (float*)d_ws;                    // 16x512x512 f32, aliased

    convert_x<<<2048, 256, 0, stream>>>(x, xb);
    transpose_w<<<dim3(16, 32), 256, 0, stream>>>(Wq, Wk, Wv, wtb);
    transpose_mem<<<dim3(8, 8), 256, 0, stream>>>(memory, memtb);

    gemm_qkv_mfma<<<dim3(16, 32), 256, 0, stream>>>(xb, wtb, qb, kbuf, vbuf);
    flash_attn_mfma<<<dim3(32, 32), 256, 0, stream>>>(qb, kbuf, vbuf, a_dot);

    row_dot_b16<<<2048, 256, 0, stream>>>(qb, mnorm, den_q, 8192);
    row_dot_b16<<<1024, 256, 0, stream>>>(kbuf, mnorm, den_k, 4096);

    gemm_amem_mfma<<<dim3(4, 64), 256, 0, stream>>>(qb, memtb, a_dot, den_q, mw, out_f);

    transpose_kelu<<<dim3(64, 8), 256, 0, stream>>>(kbuf, keluT);
    colsum_rows<<<128, 256, 0, stream>>>(keluT, mnorm, out_nrm);

    gemm_u_mfma<<<dim3(4, 32), 256, 0, stream>>>(kbuf, memtb, vbuf, den_k, uT);
    gemm_delta_mfma<<<dim3(4, 4, 16), 256, 0, stream>>>(keluT, uT, dpart);
    delta_final<<<1024, 256, 0, stream>>>(dpart, memory, out_mem);
}